// Round 13
// baseline (237.365 us; speedup 1.0000x reference)
//
#include <hip/hip_runtime.h>
#include <hip/hip_bf16.h>

#define QKVC   2304
#define NHEAD  12
#define NTOK   577
#define NBATCH 16
#define NROWS  (NBATCH * NTOK)   // 9232 = 16*577 -> exactly 577 m-tiles of 16
#define NPAD   640
#define SCALE  0.125f
#define EPSV   1e-6f
#define KT     24                // K=768 -> 24 k-chunks of 32 (12 BK=64 tiles)
#define CH     512               // u16 per chunk: 16 rows x 32 cols, 1KB

typedef __bf16  bf16x8 __attribute__((ext_vector_type(8)));
typedef float   f32x4  __attribute__((ext_vector_type(4)));

__device__ __forceinline__ unsigned short f2bf(float f) {
    union { float f; unsigned u; } v; v.f = f;
    unsigned r = v.u + 0x7FFFu + ((v.u >> 16) & 1u);   // RNE
    return (unsigned short)(r >> 16);
}
__device__ __forceinline__ unsigned short f2bf_trunc(float f) {
    return (unsigned short)(__float_as_uint(f) >> 16);  // e>=0 only
}
__device__ __forceinline__ unsigned pack2bf(float a, float b) {
    return (unsigned)f2bf(a) | ((unsigned)f2bf(b) << 16);
}
__device__ __forceinline__ f32x4 mfma16(bf16x8 a, bf16x8 b, f32x4 c) {
    return __builtin_amdgcn_mfma_f32_16x16x32_bf16(a, b, c, 0, 0, 0);
}

// async global->LDS, 16B/lane; LDS dest = wave-uniform base + lane*16
#define GLDS16(g, l) __builtin_amdgcn_global_load_lds( \
    (const __attribute__((address_space(1))) unsigned int*)(g), \
    (__attribute__((address_space(3))) unsigned int*)(l), 16, 0, 0)

// TILED OPERAND LAYOUT (round-3, verified): operand[mtile][kchunk] = 1KB
// chunk of 16 rows x 32 cols bf16, T2 seg-swizzle baked:
// chunk[r][q*8..] = src[row r][(q ^ ((r>>1)&3))*8..]. One glds = 1KB contig.

// ------------------------------------- merged prep: x->tiled bf16 + both W^T
__device__ void transpose_tile(const float* __restrict__ src, unsigned short* __restrict__ dst,
                               int N, int bx, int by, int t) {
    __shared__ unsigned short lt[64 * 72];
    int n0 = bx * 64, k0 = by * 64;
    int kk = t >> 4, nn = (t & 15) * 4;
    for (int i = 0; i < 4; i++) {
        int kr = kk + i * 16;
        float4 v = *(const float4*)&src[(size_t)(k0 + kr) * N + n0 + nn];
        lt[(nn + 0) * 72 + kr] = f2bf(v.x);
        lt[(nn + 1) * 72 + kr] = f2bf(v.y);
        lt[(nn + 2) * 72 + kr] = f2bf(v.z);
        lt[(nn + 3) * 72 + kr] = f2bf(v.w);
    }
    __syncthreads();
    int n = t >> 2;
    int ks = (t & 3) * 16;
    int gn = n0 + n;
    int ntile = gn >> 4, r = gn & 15, s = (r >> 1) & 3;
    for (int j = 0; j < 2; j++) {
        int k = k0 + ks + j * 8;
        int kt = k >> 5;
        int q = ((k >> 3) & 3) ^ s;
        uint4 v = *(uint4*)&lt[n * 72 + ks + j * 8];
        *(uint4*)&dst[((size_t)ntile * KT + kt) * CH + r * 32 + q * 8] = v;
    }
}

#define NCHUNK (577 * KT)            // 13848 x-chunks
#define CONVB  ((NCHUNK + 15) / 16)  // 866 conversion blocks (16 chunks each)
__global__ void k_prep(const float* __restrict__ x, unsigned short* __restrict__ xbt,
                       const float* __restrict__ Wqkv, unsigned short* __restrict__ wqkvt,
                       const float* __restrict__ Wproj, unsigned short* __restrict__ wprojt) {
    int id = blockIdx.x, t = threadIdx.x;
    if (id < CONVB) {
        int cid = id * 16 + (t >> 4);
        if (cid < NCHUNK) {
            int r = t & 15;
            int mt = cid / KT, kt = cid - mt * KT;
            const float* src = x + ((size_t)mt * 16 + r) * 768 + kt * 32;
            int s = (r >> 1) & 3;
            unsigned short* dst = xbt + (size_t)cid * CH + r * 32;
            #pragma unroll
            for (int q = 0; q < 4; q++) {
                int g = q ^ s;
                float4 v0 = *(const float4*)(src + g * 8);
                float4 v1 = *(const float4*)(src + g * 8 + 4);
                uint4 u;
                u.x = pack2bf(v0.x, v0.y);
                u.y = pack2bf(v0.z, v0.w);
                u.z = pack2bf(v1.x, v1.y);
                u.w = pack2bf(v1.z, v1.w);
                *(uint4*)(dst + q * 8) = u;
            }
        }
    } else if (id < CONVB + 432) {
        int i2 = id - CONVB;                    // qkv W^T: 36 x 12
        transpose_tile(Wqkv, wqkvt, QKVC, i2 % 36, i2 / 36, t);
    } else {
        int i2 = id - CONVB - 432;              // proj W^T: 12 x 12
        transpose_tile(Wproj, wprojt, 768, i2 % 12, i2 / 12, t);
    }
}

// -------------------------------------------------- 256x256 GEMM, K=768
// m201-style 8-PHASE schedule (T3+T4), derived for K=768 = 12 BK=64 tiles.
// 8 waves (2M x 4N), per-wave C = 128x64 -> acc[8][4] (128 AGPR; 2 waves/
// SIMD at <=256 regs, launch_bounds(512,2) -- round-10 spill lesson).
// LDS 128KiB: A 2buf x 32KB @0, B 2buf x 32KB @32768(u16), chunk layout +
// baked swizzle identical to the verified round-3 kernel.
// Tile tau -> buf tau&1. Phase p=(mh*2+nh) of tile tau reads unit A_mh
// (m-frags 4mh..4mh+4, both wm halves) and B_nh (n-frag-pairs 2nh..2nh+1,
// all wn). Unit last-read phases: A_0:p1, B_0:p2, A_1:p3, B_1:p3.
// STAGE SCHEDULE (1 unit = 16KB = 2 glds/wave per phase):
//   (tau,p0): A_1(tau+1)  [other buf; prev A_1(tau-1) read ended (tau-1,p3)]
//   (tau,p1): B_1(tau+1)  [other buf; prev B_1(tau-1) ended (tau-1,p3)]
//   (tau,p2): A_0(tau+2)  [same buf; prev A_0(tau) read ended p1 < p2]
//   (tau,p3): B_0(tau+2)  [same buf; prev B_0(tau) read ended p2 < p3]
// All stages issue AFTER the closing barrier of the unit's last-reader
// phase -> land-time races impossible. COUNTED vmcnt (never a drain in
// steady state), placed before the closing barrier so the following
// phase's ds_reads are globally safe:
//   end of p0: vmcnt(6)  ensures B_1(tau) (+older A_1(tau)) landed
//   end of p3: vmcnt(8)  ensures A_0/B_0(tau+1) landed
// Tail (stages skipped when tau+1/tau+2 >= 12): exact counts vmcnt(4) at
// (10,p3) and vmcnt(0) at (11,p0); nothing outstanding after.
// Accumulation is K-ascending in 32-steps -> bit-identical to round 3.
template <bool F32OUT>
__global__ __launch_bounds__(512, 2)
void k_gemm(const unsigned short* __restrict__ A, const unsigned short* __restrict__ B,
            const float* __restrict__ bias, void* __restrict__ outp, int Ncols,
            unsigned short* __restrict__ vt) {
    __shared__ unsigned short SL[65536];   // 128KiB
    int t = threadIdx.x;
    int lane = t & 63, wave = t >> 6, quad = lane >> 4, l15 = lane & 15;
    int wm = wave >> 2, wn = wave & 3;     // 2M x 4N wave grid
    int nT = Ncols >> 8;                   // 256-wide n-tiles
    int nwg = gridDim.x;

    // bijective XCD chunk swizzle (m204), m-major
    int q8 = nwg >> 3, r8 = nwg & 7;
    int xcd = blockIdx.x & 7, idx = blockIdx.x >> 3;
    int wg = (xcd < r8 ? xcd * (q8 + 1) : r8 * (q8 + 1) + (xcd - r8) * q8) + idx;
    int m0 = (wg / nT) * 256;
    int n0 = (wg % nT) * 256;

    unsigned ro = (unsigned)(quad ^ ((l15 >> 1) & 3)) * 8u;  // T2 read side

    int mwA = (wave & 3) + 8 * (wave >> 2);    // wave's m-tile slot (+4*mh)
    int nwB = (wave & 1) + 4 * (wave >> 1);    // wave's n-tile slot (+2*nh)

    auto SA = [&](int mh, int tau) {           // stage unit A_mh(tau): 2 glds
        int ml = 4 * mh + mwA;                 // local mtile 0..15
        unsigned dst = (unsigned)(tau & 1) * 16384u + (unsigned)ml * 1024u;
        const unsigned short* g =
            A + ((size_t)((m0 >> 4) + ml) * KT + tau * 2) * CH + lane * 8;
        GLDS16(g,      &SL[dst]);
        GLDS16(g + CH, &SL[dst + 512]);
    };
    auto SB = [&](int nh, int tau) {           // stage unit B_nh(tau): 2 glds
        int nl = 2 * nh + nwB;                 // local ntile 0..15
        unsigned dst = 32768u + (unsigned)(tau & 1) * 16384u + (unsigned)nl * 1024u;
        const unsigned short* g =
            B + ((size_t)((n0 >> 4) + nl) * KT + tau * 2) * CH + lane * 8;
        GLDS16(g,      &SL[dst]);
        GLDS16(g + CH, &SL[dst + 512]);
    };

    f32x4 acc[8][4] = {};

    auto PHASE = [&](int tau, int mh, int nh) {
        unsigned ab = (unsigned)(tau & 1) * 16384u;
        unsigned bb = 32768u + ab;
        bf16x8 af[4][2], bfr[2][2];
        #pragma unroll
        for (int i = 0; i < 4; i++) {
            unsigned mo = ab + (unsigned)(wm * 8 + 4 * mh + i) * 1024u + l15 * 32u + ro;
            af[i][0] = *(const bf16x8*)&SL[mo];
            af[i][1] = *(const bf16x8*)&SL[mo + 512u];
        }
        #pragma unroll
        for (int j = 0; j < 2; j++) {
            unsigned no = bb + (unsigned)(wn * 4 + 2 * nh + j) * 1024u + l15 * 32u + ro;
            bfr[j][0] = *(const bf16x8*)&SL[no];
            bfr[j][1] = *(const bf16x8*)&SL[no + 512u];
        }
        int p = mh * 2 + nh;
        if      (p == 0) { if (tau + 1 < 12) SA(1, tau + 1); }
        else if (p == 1) { if (tau + 1 < 12) SB(1, tau + 1); }
        else if (p == 2) { if (tau + 2 < 12) SA(0, tau + 2); }
        else             { if (tau + 2 < 12) SB(0, tau + 2); }
        asm volatile("s_barrier" ::: "memory");               // bar1
        __builtin_amdgcn_s_setprio(1);
        #pragma unroll
        for (int i = 0; i < 4; i++)
            #pragma unroll
            for (int j = 0; j < 2; j++) {
                acc[4*mh+i][2*nh+j] = mfma16(af[i][0], bfr[j][0], acc[4*mh+i][2*nh+j]);
                acc[4*mh+i][2*nh+j] = mfma16(af[i][1], bfr[j][1], acc[4*mh+i][2*nh+j]);
            }
        __builtin_amdgcn_s_setprio(0);
        if (p == 0) {
            if (tau == 11) asm volatile("s_waitcnt vmcnt(0)" ::: "memory");
            else           asm volatile("s_waitcnt vmcnt(6)" ::: "memory");
        } else if (p == 3) {
            if (tau == 10)     asm volatile("s_waitcnt vmcnt(4)" ::: "memory");
            else if (tau < 10) asm volatile("s_waitcnt vmcnt(8)" ::: "memory");
        }
        asm volatile("s_barrier" ::: "memory");               // bar2
    };

    // prologue: tile 0 complete + A_0/B_0 of tile 1 (12 glds in flight)
    SA(0, 0); SB(0, 0); SA(1, 0); SB(1, 0); SA(0, 1); SB(0, 1);
    asm volatile("s_waitcnt vmcnt(8)" ::: "memory");   // A_0(0),B_0(0) landed
    asm volatile("s_barrier" ::: "memory");

    for (int tau = 0; tau < 12; tau++) {
        PHASE(tau, 0, 0); PHASE(tau, 0, 1); PHASE(tau, 1, 0); PHASE(tau, 1, 1);
    }

    if constexpr (F32OUT) {
        #pragma unroll
        for (int j = 0; j < 4; j++) {
            int col = n0 + wn * 64 + j * 16 + l15;
            float bv = bias[col];
            for (int i = 0; i < 8; i++) {
                int rowm = m0 + wm * 128 + i * 16 + quad * 4;
                for (int r = 0; r < 4; r++) {
                    int m = rowm + r;
                    if (m < NROWS)
                        ((float*)outp)[(size_t)m * Ncols + col] = acc[i][j][r] + bv;
                }
            }
        }
    } else {
        // two column-half passes: repack 256x128 (stride 136) then store
        // with the round-3-verified Q/K row-store and V transposed-store.
        for (int h = 0; h < 2; h++) {
            __syncthreads();
            if ((wn >> 1) == h) {
                for (int j = 0; j < 4; j++) {
                    int colL = (wn & 1) * 64 + j * 16 + l15;
                    float bv = bias[n0 + h * 128 + colL];
                    for (int i = 0; i < 8; i++) {
                        int rowL = wm * 128 + i * 16 + quad * 4;
                        for (int r = 0; r < 4; r++)
                            SL[(rowL + r) * 136 + colL] = f2bf(acc[i][j][r] + bv);
                    }
                }
            }
            __syncthreads();
            int n0h = n0 + h * 128;
            if (n0h < 1536) {
                // Q/K cols: full-line row stores to qkvb
                for (int rr = 0; rr < 8; rr++) {
                    int row = rr * 32 + (t >> 4);
                    int m = m0 + row;
                    if (m < NROWS) {
                        uint4 v = *(uint4*)&SL[row * 136 + (t & 15) * 8];
                        *(uint4*)&((unsigned short*)outp)[(size_t)m * Ncols + n0h + (t & 15) * 8] = v;
                    }
                }
            } else {
                // V cols: transposed store into vt[((b*12+h)*64+d)*NPAD + tok]
                int h0 = (n0h - 1536) >> 6;
                for (int i2 = 0; i2 < 16; i2++) {
                    int c = wave * 16 + i2;
                    int hh = h0 + (c >> 6), d = c & 63;
                    for (int half = 0; half < 4; half++) {
                        int lr = half * 64 + lane;
                        int m = m0 + lr;
                        if (m < NROWS) {
                            unsigned bbx = (unsigned)m / 577u;
                            int tok = m - (int)bbx * 577;
                            vt[(((size_t)bbx * NHEAD + hh) * 64 + d) * NPAD + tok] =
                                SL[lr * 136 + c];
                        }
                    }
                }
            }
        }
    }
}

// --------------------------------------------------------- flash attention
// (round-3 verified) 128 q-rows per block; Q-frags direct global->VGPR;
// no max-subtraction (scores bounded); row-sum via ones-MFMA. Pad-token V
// is unwritten poison, but P==0 exactly there (pol=0, bf16 trunc) so PV is
// unaffected. Output written in the TILED chunk layout.
__global__ __launch_bounds__(256, 4)
void k_attn(const unsigned short* __restrict__ qkv, const unsigned short* __restrict__ vt,
            const float* __restrict__ policy, unsigned short* __restrict__ ao) {
    __shared__ unsigned short Ks[64 * 72];
    __shared__ unsigned short Vs[64 * 72];
    __shared__ unsigned short Ps[4][32 * 72];
    __shared__ float pol[NPAD];
    int t = threadIdx.x;
    int lane = t & 63, wave = t >> 6, quad = lane >> 4, l15 = lane & 15;
    int b = blockIdx.z, h = blockIdx.y, qt = blockIdx.x;
    const unsigned short* qbase = qkv + (size_t)(b * NTOK) * QKVC + h * 64;
    const unsigned short* kbase = qkv + (size_t)(b * NTOK) * QKVC + 768 + h * 64;
    const unsigned short* vbase = vt + (size_t)(b * NHEAD + h) * 64 * NPAD;

    for (int i = t; i < NPAD; i += 256)
        pol[i] = (i < NTOK) ? policy[b * NTOK + i] : 0.f;

    bf16x8 qf[2][2];
    for (int mi = 0; mi < 2; mi++) {
        const unsigned short* qp =
            qbase + (size_t)(qt * 128 + mi * 64 + wave * 16 + l15) * QKVC + quad * 8;
        qf[mi][0] = *(const bf16x8*)qp;
        qf[mi][1] = *(const bf16x8*)(qp + 32);
    }
    bf16x8 onesf;
    for (int j = 0; j < 8; j++) onesf[j] = (__bf16)1.0f;
    f32x4 o[2][4] = {};
    f32x4 ls[2] = {};
    int rowtok0[2];
    for (int mi = 0; mi < 2; mi++)
        rowtok0[mi] = qt * 128 + mi * 64 + wave * 16 + quad * 4;
    __syncthreads();

    for (int kt = 0; kt < 10; kt++) {
        int key0 = kt * 64;
        for (int i = t; i < 512; i += 256) {
            int row = i >> 3, seg = (i & 7) * 8;
            *(uint4*)&Ks[row * 72 + seg] = *(const uint4*)&kbase[(size_t)(key0 + row) * QKVC + seg];
            *(uint4*)&Vs[row * 72 + seg] = *(const uint4*)&vbase[(size_t)row * NPAD + key0 + seg];
        }
        __syncthreads();

        for (int ci = 0; ci < 4; ci++) {
            bf16x8 kf0 = *(const bf16x8*)&Ks[(ci * 16 + l15) * 72 + quad * 8];
            bf16x8 kf1 = *(const bf16x8*)&Ks[(ci * 16 + l15) * 72 + 32 + quad * 8];
            int col = key0 + ci * 16 + l15;
            float pc = pol[col];
            for (int mi = 0; mi < 2; mi++) {
                f32x4 a = {};
                a = mfma16(qf[mi][0], kf0, a);
                a = mfma16(qf[mi][1], kf1, a);
                for (int r = 0; r < 4; r++) {
                    float ap = (col == rowtok0[mi] + r) ? 1.f : pc;
                    float e = __expf(a[r] * SCALE) * ap;
                    Ps[wave][(mi * 16 + quad * 4 + r) * 72 + ci * 16 + l15] = f2bf_trunc(e);
                }
            }
        }
        __asm__ volatile("s_waitcnt lgkmcnt(0)" ::: "memory");
        bf16x8 pf[2][2];
        for (int mi = 0; mi < 2; mi++) {
            pf[mi][0] = *(const bf16x8*)&Ps[wave][(mi * 16 + l15) * 72 + quad * 8];
            pf[mi][1] = *(const bf16x8*)&Ps[wave][(mi * 16 + l15) * 72 + 32 + quad * 8];
            ls[mi] = mfma16(pf[mi][0], onesf, ls[mi]);
            ls[mi] = mfma16(pf[mi][1], onesf, ls[mi]);
        }
        for (int di = 0; di < 4; di++) {
            bf16x8 vf0 = *(const bf16x8*)&Vs[(di * 16 + l15) * 72 + quad * 8];
            bf16x8 vf1 = *(const bf16x8*)&Vs[(di * 16 + l15) * 72 + 32 + quad * 8];
            for (int mi = 0; mi < 2; mi++) {
                o[mi][di] = mfma16(pf[mi][0], vf0, o[mi][di]);
                o[mi][di] = mfma16(pf[mi][1], vf1, o[mi][di]);
            }
        }
        __syncthreads();
    }

    for (int mi = 0; mi < 2; mi++) {
        for (int r = 0; r < 4; r++) {
            int tok = rowtok0[mi] + r;
            if (tok < NTOK) {
                float inv = __builtin_amdgcn_rcpf(ls[mi][r] + EPSV);
                int m = b * NTOK + tok;
                int mt = m >> 4, rr = m & 15, s = (rr >> 1) & 3;
                unsigned short* dst = ao + ((size_t)mt * KT) * CH + rr * 32;
                for (int di = 0; di < 4; di++) {
                    int k = h * 64 + di * 16 + l15;
                    int kt2 = k >> 5;
                    int q = ((k >> 3) & 3) ^ s;
                    dst[(size_t)kt2 * CH + q * 8 + (l15 & 7)] =
                        f2bf(o[mi][di][r] * inv);
                }
            }
        }
    }
}

// ------------------------------------------------------------------ launch
extern "C" void kernel_launch(void* const* d_in, const int* in_sizes, int n_in,
                              void* d_out, int out_size, void* d_ws, size_t ws_size,
                              hipStream_t stream) {
    const float* x      = (const float*)d_in[0];
    const float* policy = (const float*)d_in[1];
    const float* Wqkv   = (const float*)d_in[2];
    const float* bqkv   = (const float*)d_in[3];
    const float* Wproj  = (const float*)d_in[4];
    const float* bproj  = (const float*)d_in[5];
    float* out = (float*)d_out;

    // workspace carve. xb/ao alias (xb dead before ao written); both chunk-
    // tiled. GEMM A-staging over-reads up to ~370KB past xb/ao end for
    // m-tiles 577..591 (absorbed by wqkvt+wprojt, masked in epilogue);
    // attention Q/K over-reads <=300KB past qkvb (absorbed by vt).
    unsigned short* p = (unsigned short*)d_ws;
    unsigned short* xb     = p;
    unsigned short* ao     = p; p += (size_t)NROWS * 768;
    unsigned short* wqkvt  = p; p += (size_t)QKVC * 768;
    unsigned short* wprojt = p; p += (size_t)768 * 768;
    unsigned short* qkvb   = p; p += (size_t)NROWS * QKVC;
    unsigned short* vt     = p; p += (size_t)NBATCH * NHEAD * 64 * NPAD;

    int mT = (NROWS + 255) / 256;   // 37 m-tiles of 256

    k_prep<<<CONVB + 432 + 144, 256, 0, stream>>>(x, xb, Wqkv, wqkvt, Wproj, wprojt);
    k_gemm<false><<<mT * (QKVC / 256), 512, 0, stream>>>(
        xb, wqkvt, bqkv, (void*)qkvb, QKVC, vt);
    k_attn<<<dim3(NPAD / 128, NHEAD, NBATCH), 256, 0, stream>>>(qkvb, vt, policy, ao);
    k_gemm<true><<<mT * (768 / 256), 512, 0, stream>>>(
        ao, wprojt, bproj, (void*)out, 768, nullptr);
}